// Round 1
// baseline (8163.163 us; speedup 1.0000x reference)
//
#include <hip/hip_runtime.h>
#include <math.h>

// Problem constants
// B=16, T=512, F=512, H=8, D=64; rows = B*T = 8192

static __device__ __forceinline__ float sigmoidf_(float x) {
    return 1.0f / (1.0f + __expf(-x));
}

// ---------------- generic tiled fp32 GEMM: C[M,N] = A[M,K]@B[K,N] (+bias[N]) (+resid[M,N]) ----
__global__ __launch_bounds__(256)
void gemm_f32(const float* __restrict__ A, const float* __restrict__ B,
              const float* __restrict__ bias, const float* __restrict__ resid,
              float* __restrict__ C, int M, int N, int K)
{
    __shared__ float As[16][68];
    __shared__ float Bs[16][68];
    const int tid = threadIdx.x;
    const int bm = blockIdx.x * 64;
    const int bn = blockIdx.y * 64;
    const int tx = tid & 15;      // n dir
    const int ty = tid >> 4;      // m dir
    const int mA = tid >> 2, k4A = (tid & 3) * 4;
    const int kB = tid >> 4, n4B = (tid & 15) * 4;
    float acc[4][4] = {};
    for (int k0 = 0; k0 < K; k0 += 16) {
        const float4 av = *(const float4*)(A + (size_t)(bm + mA) * K + k0 + k4A);
        const float4 bv = *(const float4*)(B + (size_t)(k0 + kB) * N + bn + n4B);
        As[k4A + 0][mA] = av.x; As[k4A + 1][mA] = av.y;
        As[k4A + 2][mA] = av.z; As[k4A + 3][mA] = av.w;
        *(float4*)&Bs[kB][n4B] = bv;
        __syncthreads();
#pragma unroll
        for (int k = 0; k < 16; ++k) {
            const float4 a = *(const float4*)&As[k][ty * 4];
            const float4 b = *(const float4*)&Bs[k][tx * 4];
            const float ar[4] = {a.x, a.y, a.z, a.w};
            const float br[4] = {b.x, b.y, b.z, b.w};
#pragma unroll
            for (int i = 0; i < 4; ++i)
#pragma unroll
                for (int j = 0; j < 4; ++j)
                    acc[i][j] = fmaf(ar[i], br[j], acc[i][j]);
        }
        __syncthreads();
    }
#pragma unroll
    for (int i = 0; i < 4; ++i) {
        const int row = bm + ty * 4 + i;
        const int col = bn + tx * 4;
        float4 o = {acc[i][0], acc[i][1], acc[i][2], acc[i][3]};
        if (bias) {
            const float4 bb = *(const float4*)(bias + col);
            o.x += bb.x; o.y += bb.y; o.z += bb.z; o.w += bb.w;
        }
        if (resid) {
            const float4 rr = *(const float4*)(resid + (size_t)row * N + col);
            o.x += rr.x; o.y += rr.y; o.z += rr.z; o.w += rr.w;
        }
        *(float4*)(C + (size_t)row * N + col) = o;
    }
}

// ---------------- fused attention per (b, h, 64-row q tile); full score block in LDS ----------
__global__ __launch_bounds__(256)
void attn_f32(const float* __restrict__ q, const float* __restrict__ k,
              const float* __restrict__ v, float* __restrict__ ctx)
{
    __shared__ float S[64][512];    // 128 KB
    __shared__ float KV[64][68];    // 17.4 KB
    const int tid = threadIdx.x;
    const int wg = blockIdx.x;
    const int qt = wg & 7, h = (wg >> 3) & 7, b = wg >> 6;
    const int r = tid >> 2, quad = tid & 3;
    const int t0 = qt * 64;

    float4 qreg[16];
    {
        const float* qrow = q + ((size_t)(b * 512 + t0 + r) * 512) + h * 64;
#pragma unroll
        for (int i = 0; i < 16; ++i) {
            float4 t = *(const float4*)(qrow + i * 4);
            t.x *= 0.125f; t.y *= 0.125f; t.z *= 0.125f; t.w *= 0.125f;
            qreg[i] = t;
        }
    }
    // phase 1: scores S[r][0..511]
    for (int st = 0; st < 8; ++st) {
        {
            const int s = tid >> 2, d0 = quad * 16;
            const float* krow = k + ((size_t)(b * 512 + st * 64 + s) * 512) + h * 64 + d0;
#pragma unroll
            for (int j = 0; j < 4; ++j)
                *(float4*)&KV[s][d0 + j * 4] = *(const float4*)(krow + j * 4);
        }
        __syncthreads();
        const int sbase = quad * 16;
#pragma unroll 4
        for (int sp = 0; sp < 16; ++sp) {
            const int s = sbase + sp;
            float accd = 0.f;
#pragma unroll
            for (int kk = 0; kk < 16; ++kk) {
                const float4 kv = *(const float4*)&KV[s][kk * 4];
                accd += qreg[kk].x * kv.x + qreg[kk].y * kv.y +
                        qreg[kk].z * kv.z + qreg[kk].w * kv.w;
            }
            S[r][st * 64 + s] = accd;
        }
        __syncthreads();
    }
    // phase 2: softmax over row r (4 threads x 128 cols each)
    const int c0 = quad * 128;
    float mx = -1e30f;
    for (int c4 = 0; c4 < 32; ++c4) {
        const float4 sv = *(const float4*)&S[r][c0 + c4 * 4];
        mx = fmaxf(mx, fmaxf(fmaxf(sv.x, sv.y), fmaxf(sv.z, sv.w)));
    }
    mx = fmaxf(mx, __shfl_xor(mx, 1));
    mx = fmaxf(mx, __shfl_xor(mx, 2));
    float sum = 0.f;
    for (int c4 = 0; c4 < 32; ++c4) {
        float4 sv = *(const float4*)&S[r][c0 + c4 * 4];
        sv.x = __expf(sv.x - mx); sv.y = __expf(sv.y - mx);
        sv.z = __expf(sv.z - mx); sv.w = __expf(sv.w - mx);
        sum += sv.x + sv.y + sv.z + sv.w;
        *(float4*)&S[r][c0 + c4 * 4] = sv;
    }
    sum += __shfl_xor(sum, 1);
    sum += __shfl_xor(sum, 2);
    const float inv = 1.0f / sum;
    __syncthreads();
    // phase 3: O[r][d0..d0+15] = P @ V
    float o[16] = {};
    const int d0 = quad * 16;
    for (int st = 0; st < 8; ++st) {
        {
            const int s = tid >> 2;
            const float* vrow = v + ((size_t)(b * 512 + st * 64 + s) * 512) + h * 64 + d0;
#pragma unroll
            for (int j = 0; j < 4; ++j)
                *(float4*)&KV[s][d0 + j * 4] = *(const float4*)(vrow + j * 4);
        }
        __syncthreads();
        for (int s4 = 0; s4 < 16; ++s4) {
            const float4 p = *(const float4*)&S[r][st * 64 + s4 * 4];
            const float pv[4] = {p.x, p.y, p.z, p.w};
#pragma unroll
            for (int jj = 0; jj < 4; ++jj) {
                const int s = s4 * 4 + jj;
#pragma unroll
                for (int i = 0; i < 4; ++i) {
                    const float4 vv = *(const float4*)&KV[s][d0 + i * 4];
                    o[i * 4 + 0] = fmaf(pv[jj], vv.x, o[i * 4 + 0]);
                    o[i * 4 + 1] = fmaf(pv[jj], vv.y, o[i * 4 + 1]);
                    o[i * 4 + 2] = fmaf(pv[jj], vv.z, o[i * 4 + 2]);
                    o[i * 4 + 3] = fmaf(pv[jj], vv.w, o[i * 4 + 3]);
                }
            }
        }
        __syncthreads();
    }
    float* crow = ctx + ((size_t)(b * 512 + t0 + r) * 512) + h * 64 + d0;
#pragma unroll
    for (int i = 0; i < 4; ++i) {
        const float4 t = {o[i * 4 + 0] * inv, o[i * 4 + 1] * inv,
                          o[i * 4 + 2] * inv, o[i * 4 + 3] * inv};
        *(float4*)(crow + i * 4) = t;
    }
}

// ---------------- layernorm over rows of 512 (1 wave per row, 4 rows per block) --------------
__global__ __launch_bounds__(256)
void ln_f32(const float* __restrict__ in, float* __restrict__ out,
            const float* __restrict__ g, const float* __restrict__ bb)
{
    const int lane = threadIdx.x & 63;
    const int row = blockIdx.x * 4 + (threadIdx.x >> 6);
    const float* x = in + (size_t)row * 512;
    const float4 a = *(const float4*)(x + lane * 4);
    const float4 c = *(const float4*)(x + 256 + lane * 4);
    float s = a.x + a.y + a.z + a.w + c.x + c.y + c.z + c.w;
#pragma unroll
    for (int off = 1; off < 64; off <<= 1) s += __shfl_xor(s, off);
    const float mu = s * (1.0f / 512.0f);
    float vs = 0.f;
    vs += (a.x - mu) * (a.x - mu) + (a.y - mu) * (a.y - mu);
    vs += (a.z - mu) * (a.z - mu) + (a.w - mu) * (a.w - mu);
    vs += (c.x - mu) * (c.x - mu) + (c.y - mu) * (c.y - mu);
    vs += (c.z - mu) * (c.z - mu) + (c.w - mu) * (c.w - mu);
#pragma unroll
    for (int off = 1; off < 64; off <<= 1) vs += __shfl_xor(vs, off);
    const float rstd = rsqrtf(vs * (1.0f / 512.0f) + 1e-3f);
    const float4 g1 = *(const float4*)(g + lane * 4);
    const float4 g2 = *(const float4*)(g + 256 + lane * 4);
    const float4 b1 = *(const float4*)(bb + lane * 4);
    const float4 b2 = *(const float4*)(bb + 256 + lane * 4);
    float* y = out + (size_t)row * 512;
    const float4 o1 = {(a.x - mu) * rstd * g1.x + b1.x, (a.y - mu) * rstd * g1.y + b1.y,
                       (a.z - mu) * rstd * g1.z + b1.z, (a.w - mu) * rstd * g1.w + b1.w};
    const float4 o2 = {(c.x - mu) * rstd * g2.x + b2.x, (c.y - mu) * rstd * g2.y + b2.y,
                       (c.z - mu) * rstd * g2.z + b2.z, (c.w - mu) * rstd * g2.w + b2.w};
    *(float4*)(y + lane * 4) = o1;
    *(float4*)(y + 256 + lane * 4) = o2;
}

// ---------------- transpose gru_rk [512][1536] -> rkT [1536][512] ----------------------------
__global__ __launch_bounds__(256)
void transpose_rk(const float* __restrict__ rk, float* __restrict__ rkT)
{
    const int idx = blockIdx.x * 256 + threadIdx.x;   // 1536*512 total
    const int c = idx >> 9, kk = idx & 511;
    rkT[idx] = rk[kk * 1536 + c];
}

// ---------------- one GRU timestep: h_out = step(h_in) ; g_out[:,t,:] = h_out ----------------
// grid 32 WGs x 256 thr; WG owns 16 h-cols; thread = (b = tid&15, cb = tid>>4)
__global__ __launch_bounds__(256)
void gru_step(const float* __restrict__ rkT, const float* __restrict__ xp,
              const float* __restrict__ rb, const float* __restrict__ hin,
              float* __restrict__ hout, float* __restrict__ gout, int t)
{
    __shared__ float hs[16][516];
    const int tid = threadIdx.x;
    const int b = tid & 15;
    const int cb = tid >> 4;               // 0..15
    const int c = blockIdx.x * 16 + cb;    // h col (0..511)
    // stage full h into LDS
    {
        const int lb = tid >> 4;           // row 0..15
        const int ch = (tid & 15) * 32;    // 32 floats per thread
#pragma unroll
        for (int i = 0; i < 8; ++i) {
            const float4 vv = *(const float4*)(hin + (size_t)lb * 512 + ch + i * 4);
            *(float4*)&hs[lb][ch + i * 4] = vv;
        }
    }
    __syncthreads();
    const float* wz = rkT + (size_t)(c) * 512;
    const float* wr = rkT + (size_t)(c + 512) * 512;
    const float* wh = rkT + (size_t)(c + 1024) * 512;
    float az = 0.f, ar = 0.f, ah = 0.f;
#pragma unroll 4
    for (int k4 = 0; k4 < 512; k4 += 4) {
        const float4 hv = *(const float4*)&hs[b][k4];
        const float4 z4 = *(const float4*)(wz + k4);
        const float4 r4 = *(const float4*)(wr + k4);
        const float4 h4 = *(const float4*)(wh + k4);
        az += hv.x * z4.x + hv.y * z4.y + hv.z * z4.z + hv.w * z4.w;
        ar += hv.x * r4.x + hv.y * r4.y + hv.z * r4.z + hv.w * r4.w;
        ah += hv.x * h4.x + hv.y * h4.y + hv.z * h4.z + hv.w * h4.w;
    }
    az += rb[c]; ar += rb[c + 512]; ah += rb[c + 1024];
    const float* xrow = xp + ((size_t)(b * 512 + t)) * 1536;
    const float xz = xrow[c], xr = xrow[c + 512], xh = xrow[c + 1024];
    const float z = sigmoidf_(xz + az);
    const float rr = sigmoidf_(xr + ar);
    const float hh = fmaxf(xh + rr * ah, 0.f);         // activation = relu
    const float hold = hs[b][c];
    const float hnew = z * hold + (1.f - z) * hh;
    hout[(size_t)b * 512 + c] = hnew;
    gout[((size_t)(b * 512 + t)) * 512 + c] = hnew;
}

extern "C" void kernel_launch(void* const* d_in, const int* in_sizes, int n_in,
                              void* d_out, int out_size, void* d_ws, size_t ws_size,
                              hipStream_t stream)
{
    const float* x     = (const float*)d_in[0];
    const float* Wq    = (const float*)d_in[1];
    const float* bq    = (const float*)d_in[2];
    const float* Wk    = (const float*)d_in[3];
    const float* bk    = (const float*)d_in[4];
    const float* Wv    = (const float*)d_in[5];
    const float* bv    = (const float*)d_in[6];
    const float* Wo    = (const float*)d_in[7];
    const float* bo    = (const float*)d_in[8];
    const float* ln1g  = (const float*)d_in[9];
    const float* ln1b  = (const float*)d_in[10];
    const float* gruk  = (const float*)d_in[11];
    const float* grurk = (const float*)d_in[12];
    const float* grub  = (const float*)d_in[13];
    const float* Wd    = (const float*)d_in[14];
    const float* bd    = (const float*)d_in[15];
    const float* ln2g  = (const float*)d_in[16];
    const float* ln2b  = (const float*)d_in[17];
    float* out = (float*)d_out;

    const size_t SZ = (size_t)8192 * 512;
    float* R0  = (float*)d_ws;         // q ; later xp spans R0..R2 ; later t2 region
    float* R1  = R0 + SZ;              // k
    float* R2  = R0 + 2 * SZ;          // v
    float* R3  = R0 + 3 * SZ;          // ctx ; later GRU output g
    float* R4  = R0 + 4 * SZ;          // a+x -> x1 (LN1 in place)
    float* rkT = R0 + 5 * SZ;          // 1536*512
    float* hA  = rkT + (size_t)1536 * 512;
    float* hB  = hA + 16 * 512;

    const dim3 blk(256);
    const dim3 g512(8192 / 64, 512 / 64);
    const dim3 g1536(8192 / 64, 1536 / 64);

    // QKV projections
    gemm_f32<<<g512, blk, 0, stream>>>(x, Wq, bq, nullptr, R0, 8192, 512, 512);
    gemm_f32<<<g512, blk, 0, stream>>>(x, Wk, bk, nullptr, R1, 8192, 512, 512);
    gemm_f32<<<g512, blk, 0, stream>>>(x, Wv, bv, nullptr, R2, 8192, 512, 512);
    // attention
    attn_f32<<<dim3(1024), blk, 0, stream>>>(R0, R1, R2, R3);
    // output projection + residual, then LN1 (in place -> x1 in R4)
    gemm_f32<<<g512, blk, 0, stream>>>(R3, Wo, bo, x, R4, 8192, 512, 512);
    ln_f32<<<dim3(2048), blk, 0, stream>>>(R4, R4, ln1g, ln1b);
    // GRU input projection xp = x1 @ gru_k + gru_b[0]  (spans R0..R2)
    gemm_f32<<<g1536, blk, 0, stream>>>(R4, gruk, grub, nullptr, R0, 8192, 1536, 512);
    // recurrent weight transpose + h0 = 0
    transpose_rk<<<dim3(3072), blk, 0, stream>>>(grurk, rkT);
    hipMemsetAsync(hA, 0, 16 * 512 * sizeof(float), stream);
    // sequential GRU (ping-pong h buffers), writes g into R3
    for (int t = 0; t < 512; ++t) {
        float* hin  = (t & 1) ? hB : hA;
        float* hout = (t & 1) ? hA : hB;
        gru_step<<<dim3(32), blk, 0, stream>>>(rkT, R0, grub + 1536, hin, hout, R3, t);
    }
    // Dense + residual x1, then LN2 -> out
    gemm_f32<<<g512, blk, 0, stream>>>(R3, Wd, bd, R4, R1, 8192, 512, 512);
    ln_f32<<<dim3(2048), blk, 0, stream>>>(R1, out, ln2g, ln2b);
}

// Round 2
// 3396.989 us; speedup vs baseline: 2.4031x; 2.4031x over previous
//
#include <hip/hip_runtime.h>
#include <math.h>

// B=16, T=512, F=512, H=8, D=64; rows = B*T = 8192
#define NWG 32   // persistent GRU workgroups (1 wave each)

typedef __attribute__((ext_vector_type(8))) short bf16x8;
typedef __attribute__((ext_vector_type(4))) float f32x4;

static __device__ __forceinline__ float sigmoidf_(float x) {
    return 1.0f / (1.0f + __expf(-x));
}
static __device__ __forceinline__ unsigned short f2bf(float f) {
    unsigned int u = __float_as_uint(f);
    u += 0x7fffu + ((u >> 16) & 1u);
    return (unsigned short)(u >> 16);
}

// ---------------- generic tiled fp32 GEMM: C[M,N] = A[M,K]@B[K,N] (+bias[N]) (+resid[M,N]) ----
__global__ __launch_bounds__(256)
void gemm_f32(const float* __restrict__ A, const float* __restrict__ B,
              const float* __restrict__ bias, const float* __restrict__ resid,
              float* __restrict__ C, int M, int N, int K)
{
    __shared__ float As[16][68];
    __shared__ float Bs[16][68];
    const int tid = threadIdx.x;
    const int bm = blockIdx.x * 64;
    const int bn = blockIdx.y * 64;
    const int tx = tid & 15;      // n dir
    const int ty = tid >> 4;      // m dir
    const int mA = tid >> 2, k4A = (tid & 3) * 4;
    const int kB = tid >> 4, n4B = (tid & 15) * 4;
    float acc[4][4] = {};
    for (int k0 = 0; k0 < K; k0 += 16) {
        const float4 av = *(const float4*)(A + (size_t)(bm + mA) * K + k0 + k4A);
        const float4 bv = *(const float4*)(B + (size_t)(k0 + kB) * N + bn + n4B);
        As[k4A + 0][mA] = av.x; As[k4A + 1][mA] = av.y;
        As[k4A + 2][mA] = av.z; As[k4A + 3][mA] = av.w;
        *(float4*)&Bs[kB][n4B] = bv;
        __syncthreads();
#pragma unroll
        for (int k = 0; k < 16; ++k) {
            const float4 a = *(const float4*)&As[k][ty * 4];
            const float4 b = *(const float4*)&Bs[k][tx * 4];
            const float ar[4] = {a.x, a.y, a.z, a.w};
            const float br[4] = {b.x, b.y, b.z, b.w};
#pragma unroll
            for (int i = 0; i < 4; ++i)
#pragma unroll
                for (int j = 0; j < 4; ++j)
                    acc[i][j] = fmaf(ar[i], br[j], acc[i][j]);
        }
        __syncthreads();
    }
#pragma unroll
    for (int i = 0; i < 4; ++i) {
        const int row = bm + ty * 4 + i;
        const int col = bn + tx * 4;
        float4 o = {acc[i][0], acc[i][1], acc[i][2], acc[i][3]};
        if (bias) {
            const float4 bb = *(const float4*)(bias + col);
            o.x += bb.x; o.y += bb.y; o.z += bb.z; o.w += bb.w;
        }
        if (resid) {
            const float4 rr = *(const float4*)(resid + (size_t)row * N + col);
            o.x += rr.x; o.y += rr.y; o.z += rr.z; o.w += rr.w;
        }
        *(float4*)(C + (size_t)row * N + col) = o;
    }
}

// ---------------- fused attention per (b, h, 64-row q tile); full score block in LDS ----------
__global__ __launch_bounds__(256)
void attn_f32(const float* __restrict__ q, const float* __restrict__ k,
              const float* __restrict__ v, float* __restrict__ ctx)
{
    __shared__ float S[64][512];    // 128 KB
    __shared__ float KV[64][68];    // 17.4 KB
    const int tid = threadIdx.x;
    const int wg = blockIdx.x;
    const int qt = wg & 7, h = (wg >> 3) & 7, b = wg >> 6;
    const int r = tid >> 2, quad = tid & 3;
    const int t0 = qt * 64;

    float4 qreg[16];
    {
        const float* qrow = q + ((size_t)(b * 512 + t0 + r) * 512) + h * 64;
#pragma unroll
        for (int i = 0; i < 16; ++i) {
            float4 t = *(const float4*)(qrow + i * 4);
            t.x *= 0.125f; t.y *= 0.125f; t.z *= 0.125f; t.w *= 0.125f;
            qreg[i] = t;
        }
    }
    // phase 1: scores S[r][0..511]
    for (int st = 0; st < 8; ++st) {
        {
            const int s = tid >> 2, d0 = quad * 16;
            const float* krow = k + ((size_t)(b * 512 + st * 64 + s) * 512) + h * 64 + d0;
#pragma unroll
            for (int j = 0; j < 4; ++j)
                *(float4*)&KV[s][d0 + j * 4] = *(const float4*)(krow + j * 4);
        }
        __syncthreads();
        const int sbase = quad * 16;
#pragma unroll 4
        for (int sp = 0; sp < 16; ++sp) {
            const int s = sbase + sp;
            float accd = 0.f;
#pragma unroll
            for (int kk = 0; kk < 16; ++kk) {
                const float4 kv = *(const float4*)&KV[s][kk * 4];
                accd += qreg[kk].x * kv.x + qreg[kk].y * kv.y +
                        qreg[kk].z * kv.z + qreg[kk].w * kv.w;
            }
            S[r][st * 64 + s] = accd;
        }
        __syncthreads();
    }
    // phase 2: softmax over row r (4 threads x 128 cols each)
    const int c0 = quad * 128;
    float mx = -1e30f;
    for (int c4 = 0; c4 < 32; ++c4) {
        const float4 sv = *(const float4*)&S[r][c0 + c4 * 4];
        mx = fmaxf(mx, fmaxf(fmaxf(sv.x, sv.y), fmaxf(sv.z, sv.w)));
    }
    mx = fmaxf(mx, __shfl_xor(mx, 1));
    mx = fmaxf(mx, __shfl_xor(mx, 2));
    float sum = 0.f;
    for (int c4 = 0; c4 < 32; ++c4) {
        float4 sv = *(const float4*)&S[r][c0 + c4 * 4];
        sv.x = __expf(sv.x - mx); sv.y = __expf(sv.y - mx);
        sv.z = __expf(sv.z - mx); sv.w = __expf(sv.w - mx);
        sum += sv.x + sv.y + sv.z + sv.w;
        *(float4*)&S[r][c0 + c4 * 4] = sv;
    }
    sum += __shfl_xor(sum, 1);
    sum += __shfl_xor(sum, 2);
    const float inv = 1.0f / sum;
    __syncthreads();
    // phase 3: O[r][d0..d0+15] = P @ V
    float o[16] = {};
    const int d0 = quad * 16;
    for (int st = 0; st < 8; ++st) {
        {
            const int s = tid >> 2;
            const float* vrow = v + ((size_t)(b * 512 + st * 64 + s) * 512) + h * 64 + d0;
#pragma unroll
            for (int j = 0; j < 4; ++j)
                *(float4*)&KV[s][d0 + j * 4] = *(const float4*)(vrow + j * 4);
        }
        __syncthreads();
        for (int s4 = 0; s4 < 16; ++s4) {
            const float4 p = *(const float4*)&S[r][st * 64 + s4 * 4];
            const float pv[4] = {p.x, p.y, p.z, p.w};
#pragma unroll
            for (int jj = 0; jj < 4; ++jj) {
                const int s = s4 * 4 + jj;
#pragma unroll
                for (int i = 0; i < 4; ++i) {
                    const float4 vv = *(const float4*)&KV[s][d0 + i * 4];
                    o[i * 4 + 0] = fmaf(pv[jj], vv.x, o[i * 4 + 0]);
                    o[i * 4 + 1] = fmaf(pv[jj], vv.y, o[i * 4 + 1]);
                    o[i * 4 + 2] = fmaf(pv[jj], vv.z, o[i * 4 + 2]);
                    o[i * 4 + 3] = fmaf(pv[jj], vv.w, o[i * 4 + 3]);
                }
            }
        }
        __syncthreads();
    }
    float* crow = ctx + ((size_t)(b * 512 + t0 + r) * 512) + h * 64 + d0;
#pragma unroll
    for (int i = 0; i < 4; ++i) {
        const float4 t = {o[i * 4 + 0] * inv, o[i * 4 + 1] * inv,
                          o[i * 4 + 2] * inv, o[i * 4 + 3] * inv};
        *(float4*)(crow + i * 4) = t;
    }
}

// ---------------- layernorm over rows of 512 (1 wave per row, 4 rows per block) --------------
__global__ __launch_bounds__(256)
void ln_f32(const float* __restrict__ in, float* __restrict__ out,
            const float* __restrict__ g, const float* __restrict__ bb)
{
    const int lane = threadIdx.x & 63;
    const int row = blockIdx.x * 4 + (threadIdx.x >> 6);
    const float* x = in + (size_t)row * 512;
    const float4 a = *(const float4*)(x + lane * 4);
    const float4 c = *(const float4*)(x + 256 + lane * 4);
    float s = a.x + a.y + a.z + a.w + c.x + c.y + c.z + c.w;
#pragma unroll
    for (int off = 1; off < 64; off <<= 1) s += __shfl_xor(s, off);
    const float mu = s * (1.0f / 512.0f);
    float vs = 0.f;
    vs += (a.x - mu) * (a.x - mu) + (a.y - mu) * (a.y - mu);
    vs += (a.z - mu) * (a.z - mu) + (a.w - mu) * (a.w - mu);
    vs += (c.x - mu) * (c.x - mu) + (c.y - mu) * (c.y - mu);
    vs += (c.z - mu) * (c.z - mu) + (c.w - mu) * (c.w - mu);
#pragma unroll
    for (int off = 1; off < 64; off <<= 1) vs += __shfl_xor(vs, off);
    const float rstd = rsqrtf(vs * (1.0f / 512.0f) + 1e-3f);
    const float4 g1 = *(const float4*)(g + lane * 4);
    const float4 g2 = *(const float4*)(g + 256 + lane * 4);
    const float4 b1 = *(const float4*)(bb + lane * 4);
    const float4 b2 = *(const float4*)(bb + 256 + lane * 4);
    float* y = out + (size_t)row * 512;
    const float4 o1 = {(a.x - mu) * rstd * g1.x + b1.x, (a.y - mu) * rstd * g1.y + b1.y,
                       (a.z - mu) * rstd * g1.z + b1.z, (a.w - mu) * rstd * g1.w + b1.w};
    const float4 o2 = {(c.x - mu) * rstd * g2.x + b2.x, (c.y - mu) * rstd * g2.y + b2.y,
                       (c.z - mu) * rstd * g2.z + b2.z, (c.w - mu) * rstd * g2.w + b2.w};
    *(float4*)(y + lane * 4) = o1;
    *(float4*)(y + 256 + lane * 4) = o2;
}

// ---------------- persistent GRU: one launch, 512 steps, grid barrier per step ---------------
// 32 WGs x 64 threads (1 wave). WG w owns h-cols [w*16, w*16+16).
// Recurrent weights live in VGPRs (bf16 frags) for the whole kernel.
// h state (fp32) lives in registers: lane l, reg j owns (b=(l>>4)*4+j, c=l&15).
// h exchanged via ping-pong global bf16 buffers; device-scope atomic barrier per step.
__global__ __launch_bounds__(64, 1)
void gru_persist(const float* __restrict__ rk,      // gru_rk [512][1536] fp32
                 const float* __restrict__ xp,      // [8192][1536] fp32 (bias0 included)
                 const float* __restrict__ rb,      // recurrent bias [1536]
                 unsigned short* __restrict__ hbuf, // [2][16*512] bf16 bits (buf0 zeroed)
                 float* __restrict__ gout,          // [8192][512] fp32
                 unsigned int* __restrict__ bar)    // zeroed
{
    const int w = blockIdx.x;
    const int l = threadIdx.x;
    const int lo16 = l & 15;
    const int hi4 = l >> 4;            // 0..3
    const int gc = w * 16 + lo16;      // this lane's output h-col

    // ---- preload B fragments: B[g][kt], lane slot j <-> k = kt*32 + hi4*8 + j
    bf16x8 B[3][16];
#pragma unroll
    for (int g = 0; g < 3; ++g)
#pragma unroll
        for (int kt = 0; kt < 16; ++kt) {
            bf16x8 bv;
#pragma unroll
            for (int j = 0; j < 8; ++j) {
                const int k = kt * 32 + hi4 * 8 + j;
                bv[j] = (short)f2bf(rk[(size_t)k * 1536 + g * 512 + gc]);
            }
            B[g][kt] = bv;
        }
    const float rbz = rb[gc], rbr = rb[512 + gc], rbh = rb[1024 + gc];
    float hst[4] = {0.f, 0.f, 0.f, 0.f};

    for (int t = 0; t < 512; ++t) {
        const unsigned short* hr = hbuf + (size_t)(t & 1) * (16 * 512);
        unsigned short* hw = hbuf + (size_t)((t + 1) & 1) * (16 * 512);
        // A frags: lane reads h[b=lo16][k..k+7] contiguous (same k-map as B)
        bf16x8 A[16];
#pragma unroll
        for (int kt = 0; kt < 16; ++kt)
            A[kt] = *(const bf16x8*)(hr + lo16 * 512 + kt * 32 + hi4 * 8);
        // xp loads (independent -> issue early)
        float xzv[4], xrv[4], xhv[4];
#pragma unroll
        for (int j = 0; j < 4; ++j) {
            const int b = hi4 * 4 + j;
            const float* xrow = xp + ((size_t)(b * 512 + t)) * 1536 + gc;
            xzv[j] = xrow[0];
            xrv[j] = xrow[512];
            xhv[j] = xrow[1024];
        }
        f32x4 accz = {0.f, 0.f, 0.f, 0.f};
        f32x4 accr = {0.f, 0.f, 0.f, 0.f};
        f32x4 acch = {0.f, 0.f, 0.f, 0.f};
#pragma unroll
        for (int kt = 0; kt < 16; ++kt) {
            accz = __builtin_amdgcn_mfma_f32_16x16x32_bf16(A[kt], B[0][kt], accz, 0, 0, 0);
            accr = __builtin_amdgcn_mfma_f32_16x16x32_bf16(A[kt], B[1][kt], accr, 0, 0, 0);
            acch = __builtin_amdgcn_mfma_f32_16x16x32_bf16(A[kt], B[2][kt], acch, 0, 0, 0);
        }
        // gates + state update; D layout: row b = hi4*4 + j, col = lo16
#pragma unroll
        for (int j = 0; j < 4; ++j) {
            const int b = hi4 * 4 + j;
            const float z = sigmoidf_(xzv[j] + accz[j] + rbz);
            const float r = sigmoidf_(xrv[j] + accr[j] + rbr);
            const float hh = fmaxf(xhv[j] + r * (acch[j] + rbh), 0.f);
            const float hnew = z * hst[j] + (1.f - z) * hh;
            hst[j] = hnew;
            hw[b * 512 + gc] = f2bf(hnew);
            gout[((size_t)(b * 512 + t)) * 512 + gc] = hnew;
        }
        // grid barrier (skip after last step)
        if (t < 511) {
            if (l == 0)
                __hip_atomic_fetch_add(bar, 1u, __ATOMIC_ACQ_REL, __HIP_MEMORY_SCOPE_AGENT);
            const unsigned int target = (unsigned int)(NWG * (t + 1));
            while (__hip_atomic_load(bar, __ATOMIC_ACQUIRE, __HIP_MEMORY_SCOPE_AGENT) < target) {}
        }
    }
}

extern "C" void kernel_launch(void* const* d_in, const int* in_sizes, int n_in,
                              void* d_out, int out_size, void* d_ws, size_t ws_size,
                              hipStream_t stream)
{
    const float* x     = (const float*)d_in[0];
    const float* Wq    = (const float*)d_in[1];
    const float* bq    = (const float*)d_in[2];
    const float* Wk    = (const float*)d_in[3];
    const float* bk    = (const float*)d_in[4];
    const float* Wv    = (const float*)d_in[5];
    const float* bv    = (const float*)d_in[6];
    const float* Wo    = (const float*)d_in[7];
    const float* bo    = (const float*)d_in[8];
    const float* ln1g  = (const float*)d_in[9];
    const float* ln1b  = (const float*)d_in[10];
    const float* gruk  = (const float*)d_in[11];
    const float* grurk = (const float*)d_in[12];
    const float* grub  = (const float*)d_in[13];
    const float* Wd    = (const float*)d_in[14];
    const float* bd    = (const float*)d_in[15];
    const float* ln2g  = (const float*)d_in[16];
    const float* ln2b  = (const float*)d_in[17];
    float* out = (float*)d_out;

    const size_t SZ = (size_t)8192 * 512;
    float* R0  = (float*)d_ws;         // q ; later xp spans R0..R2
    float* R1  = R0 + SZ;              // k ; later dense out
    float* R2  = R0 + 2 * SZ;          // v
    float* R3  = R0 + 3 * SZ;          // ctx ; later GRU output g
    float* R4  = R0 + 4 * SZ;          // a+x -> x1 (LN1 in place)
    unsigned short* hbuf = (unsigned short*)(R0 + 5 * SZ);   // 2*16*512 bf16
    unsigned int*   bar  = (unsigned int*)(hbuf + 2 * 16 * 512);

    const dim3 blk(256);
    const dim3 g512(8192 / 64, 512 / 64);
    const dim3 g1536(8192 / 64, 1536 / 64);

    // QKV projections
    gemm_f32<<<g512, blk, 0, stream>>>(x, Wq, bq, nullptr, R0, 8192, 512, 512);
    gemm_f32<<<g512, blk, 0, stream>>>(x, Wk, bk, nullptr, R1, 8192, 512, 512);
    gemm_f32<<<g512, blk, 0, stream>>>(x, Wv, bv, nullptr, R2, 8192, 512, 512);
    // attention
    attn_f32<<<dim3(1024), blk, 0, stream>>>(R0, R1, R2, R3);
    // output projection + residual, then LN1 (in place -> x1 in R4)
    gemm_f32<<<g512, blk, 0, stream>>>(R3, Wo, bo, x, R4, 8192, 512, 512);
    ln_f32<<<dim3(2048), blk, 0, stream>>>(R4, R4, ln1g, ln1b);
    // GRU input projection xp = x1 @ gru_k + gru_b[0]  (spans R0..R2)
    gemm_f32<<<g1536, blk, 0, stream>>>(R4, gruk, grub, nullptr, R0, 8192, 1536, 512);
    // persistent GRU: init h ping-pong + barrier counter, one launch for all 512 steps
    hipMemsetAsync(hbuf, 0, 2 * 16 * 512 * sizeof(unsigned short), stream);
    hipMemsetAsync(bar, 0, sizeof(unsigned int), stream);
    gru_persist<<<dim3(NWG), dim3(64), 0, stream>>>(grurk, R0, grub + 1536, hbuf, R3, bar);
    // Dense + residual x1, then LN2 -> out
    gemm_f32<<<g512, blk, 0, stream>>>(R3, Wd, bd, R4, R1, 8192, 512, 512);
    ln_f32<<<dim3(2048), blk, 0, stream>>>(R1, out, ln2g, ln2b);
}

// Round 3
// 3144.782 us; speedup vs baseline: 2.5958x; 1.0802x over previous
//
#include <hip/hip_runtime.h>
#include <math.h>

// B=16, T=512, F=512, H=8, D=64; rows = B*T = 8192
#define NWG 8   // persistent GRU workgroups (4 waves each -> 32 col-owner waves)

typedef __attribute__((ext_vector_type(8))) short bf16x8;
typedef __attribute__((ext_vector_type(4))) float f32x4;
typedef __attribute__((ext_vector_type(4))) unsigned short us4;

static __device__ __forceinline__ float sigmoidf_(float x) {
    return 1.0f / (1.0f + __expf(-x));
}
static __device__ __forceinline__ unsigned short f2bf(float f) {
    unsigned int u = __float_as_uint(f);
    u += 0x7fffu + ((u >> 16) & 1u);
    return (unsigned short)(u >> 16);
}
static __device__ __forceinline__ void gload_lds16(const void* g, void* l) {
    __builtin_amdgcn_global_load_lds(
        (const __attribute__((address_space(1))) unsigned int*)g,
        (__attribute__((address_space(3))) unsigned int*)l, 16, 0, 0);
}

// ---------------- fp32 -> bf16 convert --------------------------------------------------------
__global__ __launch_bounds__(256)
void f2bf_kernel(const float* __restrict__ in, unsigned short* __restrict__ out)
{
    const int i = (blockIdx.x * 256 + threadIdx.x) * 4;
    const float4 v = *(const float4*)(in + i);
    const us4 o = {f2bf(v.x), f2bf(v.y), f2bf(v.z), f2bf(v.w)};
    *(us4*)(out + i) = o;
}

// ---------------- transpose+convert: in [K][N] f32 -> out [N][K] bf16 -------------------------
__global__ __launch_bounds__(256)
void transpose_bf16(const float* __restrict__ in, unsigned short* __restrict__ out,
                    int K, int N)
{
    __shared__ float tile[32][33];
    const int n0 = blockIdx.x * 32, k0 = blockIdx.y * 32;
    const int c = threadIdx.x & 31, r8 = threadIdx.x >> 5;
#pragma unroll
    for (int i = 0; i < 4; ++i) {
        const int k = r8 + i * 8;
        tile[k][c] = in[(size_t)(k0 + k) * N + n0 + c];
    }
    __syncthreads();
#pragma unroll
    for (int i = 0; i < 4; ++i) {
        const int n = r8 + i * 8;
        out[(size_t)(n0 + n) * K + k0 + c] = f2bf(tile[c][n]);
    }
}

// ---------------- bf16 MFMA GEMM: C[M,N](f32) = A[M,K](bf16) @ Bt[N,K](bf16) ------------------
// 128x128 tile, BK=64, 4 waves; m97 structure (global_load_lds w16, ds_read_b128 frags)
__global__ __launch_bounds__(256)
void gemm_bf16(const unsigned short* __restrict__ A, const unsigned short* __restrict__ Bt,
               const float* __restrict__ bias, const float* __restrict__ resid,
               float* __restrict__ C, int M, int N, int K)
{
    __shared__ unsigned short As[128 * 64];
    __shared__ unsigned short Bs[128 * 64];
    const int tid = threadIdx.x;
    const int wave = tid >> 6, lane = tid & 63;
    const int bm = blockIdx.x * 128, bn = blockIdx.y * 128;
    const int wr = wave >> 1, wc = wave & 1;      // 2x2 wave grid, 64x64 per wave
    const int stR = lane >> 3;                    // staging row 0..7
    const int stC = (lane & 7) * 8;               // staging col (elements)

    const unsigned short* Abase = A + (size_t)(bm + wave * 32 + stR) * K + stC;
    const unsigned short* Bbase = Bt + (size_t)(bn + wave * 32 + stR) * K + stC;
    unsigned short* AsW = As + wave * 2048;
    unsigned short* BsW = Bs + wave * 2048;

    f32x4 acc[4][4] = {};
    const int fr = lane & 15;
    const int fko = (lane >> 4) * 8;

    for (int k0 = 0; k0 < K; k0 += 64) {
#pragma unroll
        for (int i = 0; i < 4; ++i) {
            gload_lds16(Abase + (size_t)i * 8 * K + k0, AsW + i * 512);
            gload_lds16(Bbase + (size_t)i * 8 * K + k0, BsW + i * 512);
        }
        __syncthreads();
        bf16x8 af[4][2], bfr[4][2];
#pragma unroll
        for (int m = 0; m < 4; ++m) {
            const unsigned short* ap = As + (wr * 64 + m * 16 + fr) * 64 + fko;
            af[m][0] = *(const bf16x8*)(ap);
            af[m][1] = *(const bf16x8*)(ap + 32);
        }
#pragma unroll
        for (int n = 0; n < 4; ++n) {
            const unsigned short* bp = Bs + (wc * 64 + n * 16 + fr) * 64 + fko;
            bfr[n][0] = *(const bf16x8*)(bp);
            bfr[n][1] = *(const bf16x8*)(bp + 32);
        }
#pragma unroll
        for (int m = 0; m < 4; ++m)
#pragma unroll
            for (int n = 0; n < 4; ++n) {
                acc[m][n] = __builtin_amdgcn_mfma_f32_16x16x32_bf16(af[m][0], bfr[n][0], acc[m][n], 0, 0, 0);
                acc[m][n] = __builtin_amdgcn_mfma_f32_16x16x32_bf16(af[m][1], bfr[n][1], acc[m][n], 0, 0, 0);
            }
        __syncthreads();
    }
    // epilogue: C/D layout col = lane&15, row = (lane>>4)*4 + j
    const int fq = lane >> 4;
#pragma unroll
    for (int n = 0; n < 4; ++n) {
        const int col = bn + wc * 64 + n * 16 + fr;
        const float bv = bias ? bias[col] : 0.f;
#pragma unroll
        for (int m = 0; m < 4; ++m) {
#pragma unroll
            for (int j = 0; j < 4; ++j) {
                const int row = bm + wr * 64 + m * 16 + fq * 4 + j;
                float v = acc[m][n][j] + bv;
                if (resid) v += resid[(size_t)row * N + col];
                C[(size_t)row * N + col] = v;
            }
        }
    }
}

// ---------------- fused attention per (b, h, 64-row q tile); writes ctx as bf16 ---------------
__global__ __launch_bounds__(256)
void attn_f32(const float* __restrict__ q, const float* __restrict__ k,
              const float* __restrict__ v, unsigned short* __restrict__ ctxb)
{
    __shared__ float S[64][512];    // 128 KB
    __shared__ float KV[64][68];    // 17.4 KB
    const int tid = threadIdx.x;
    const int wg = blockIdx.x;
    const int qt = wg & 7, h = (wg >> 3) & 7, b = wg >> 6;
    const int r = tid >> 2, quad = tid & 3;
    const int t0 = qt * 64;

    float4 qreg[16];
    {
        const float* qrow = q + ((size_t)(b * 512 + t0 + r) * 512) + h * 64;
#pragma unroll
        for (int i = 0; i < 16; ++i) {
            float4 t = *(const float4*)(qrow + i * 4);
            t.x *= 0.125f; t.y *= 0.125f; t.z *= 0.125f; t.w *= 0.125f;
            qreg[i] = t;
        }
    }
    for (int st = 0; st < 8; ++st) {
        {
            const int s = tid >> 2, d0 = quad * 16;
            const float* krow = k + ((size_t)(b * 512 + st * 64 + s) * 512) + h * 64 + d0;
#pragma unroll
            for (int j = 0; j < 4; ++j)
                *(float4*)&KV[s][d0 + j * 4] = *(const float4*)(krow + j * 4);
        }
        __syncthreads();
        const int sbase = quad * 16;
#pragma unroll 4
        for (int sp = 0; sp < 16; ++sp) {
            const int s = sbase + sp;
            float accd = 0.f;
#pragma unroll
            for (int kk = 0; kk < 16; ++kk) {
                const float4 kv = *(const float4*)&KV[s][kk * 4];
                accd += qreg[kk].x * kv.x + qreg[kk].y * kv.y +
                        qreg[kk].z * kv.z + qreg[kk].w * kv.w;
            }
            S[r][st * 64 + s] = accd;
        }
        __syncthreads();
    }
    const int c0 = quad * 128;
    float mx = -1e30f;
    for (int c4 = 0; c4 < 32; ++c4) {
        const float4 sv = *(const float4*)&S[r][c0 + c4 * 4];
        mx = fmaxf(mx, fmaxf(fmaxf(sv.x, sv.y), fmaxf(sv.z, sv.w)));
    }
    mx = fmaxf(mx, __shfl_xor(mx, 1));
    mx = fmaxf(mx, __shfl_xor(mx, 2));
    float sum = 0.f;
    for (int c4 = 0; c4 < 32; ++c4) {
        float4 sv = *(const float4*)&S[r][c0 + c4 * 4];
        sv.x = __expf(sv.x - mx); sv.y = __expf(sv.y - mx);
        sv.z = __expf(sv.z - mx); sv.w = __expf(sv.w - mx);
        sum += sv.x + sv.y + sv.z + sv.w;
        *(float4*)&S[r][c0 + c4 * 4] = sv;
    }
    sum += __shfl_xor(sum, 1);
    sum += __shfl_xor(sum, 2);
    const float inv = 1.0f / sum;
    __syncthreads();
    float o[16] = {};
    const int d0 = quad * 16;
    for (int st = 0; st < 8; ++st) {
        {
            const int s = tid >> 2;
            const float* vrow = v + ((size_t)(b * 512 + st * 64 + s) * 512) + h * 64 + d0;
#pragma unroll
            for (int j = 0; j < 4; ++j)
                *(float4*)&KV[s][d0 + j * 4] = *(const float4*)(vrow + j * 4);
        }
        __syncthreads();
        for (int s4 = 0; s4 < 16; ++s4) {
            const float4 p = *(const float4*)&S[r][st * 64 + s4 * 4];
            const float pv[4] = {p.x, p.y, p.z, p.w};
#pragma unroll
            for (int jj = 0; jj < 4; ++jj) {
                const int s = s4 * 4 + jj;
#pragma unroll
                for (int i = 0; i < 4; ++i) {
                    const float4 vv = *(const float4*)&KV[s][d0 + i * 4];
                    o[i * 4 + 0] = fmaf(pv[jj], vv.x, o[i * 4 + 0]);
                    o[i * 4 + 1] = fmaf(pv[jj], vv.y, o[i * 4 + 1]);
                    o[i * 4 + 2] = fmaf(pv[jj], vv.z, o[i * 4 + 2]);
                    o[i * 4 + 3] = fmaf(pv[jj], vv.w, o[i * 4 + 3]);
                }
            }
        }
        __syncthreads();
    }
    unsigned short* crow = ctxb + ((size_t)(b * 512 + t0 + r) * 512) + h * 64 + d0;
#pragma unroll
    for (int i = 0; i < 4; ++i) {
        const us4 t = {f2bf(o[i * 4 + 0] * inv), f2bf(o[i * 4 + 1] * inv),
                       f2bf(o[i * 4 + 2] * inv), f2bf(o[i * 4 + 3] * inv)};
        *(us4*)(crow + i * 4) = t;
    }
}

// ---------------- layernorm (rows of 512), optional bf16 side output --------------------------
__global__ __launch_bounds__(256)
void ln_f32(const float* __restrict__ in, float* __restrict__ out,
            const float* __restrict__ g, const float* __restrict__ bb,
            unsigned short* __restrict__ outb)
{
    const int lane = threadIdx.x & 63;
    const int row = blockIdx.x * 4 + (threadIdx.x >> 6);
    const float* x = in + (size_t)row * 512;
    const float4 a = *(const float4*)(x + lane * 4);
    const float4 c = *(const float4*)(x + 256 + lane * 4);
    float s = a.x + a.y + a.z + a.w + c.x + c.y + c.z + c.w;
#pragma unroll
    for (int off = 1; off < 64; off <<= 1) s += __shfl_xor(s, off);
    const float mu = s * (1.0f / 512.0f);
    float vs = 0.f;
    vs += (a.x - mu) * (a.x - mu) + (a.y - mu) * (a.y - mu);
    vs += (a.z - mu) * (a.z - mu) + (a.w - mu) * (a.w - mu);
    vs += (c.x - mu) * (c.x - mu) + (c.y - mu) * (c.y - mu);
    vs += (c.z - mu) * (c.z - mu) + (c.w - mu) * (c.w - mu);
#pragma unroll
    for (int off = 1; off < 64; off <<= 1) vs += __shfl_xor(vs, off);
    const float rstd = rsqrtf(vs * (1.0f / 512.0f) + 1e-3f);
    const float4 g1 = *(const float4*)(g + lane * 4);
    const float4 g2 = *(const float4*)(g + 256 + lane * 4);
    const float4 b1 = *(const float4*)(bb + lane * 4);
    const float4 b2 = *(const float4*)(bb + 256 + lane * 4);
    float* y = out + (size_t)row * 512;
    const float4 o1 = {(a.x - mu) * rstd * g1.x + b1.x, (a.y - mu) * rstd * g1.y + b1.y,
                       (a.z - mu) * rstd * g1.z + b1.z, (a.w - mu) * rstd * g1.w + b1.w};
    const float4 o2 = {(c.x - mu) * rstd * g2.x + b2.x, (c.y - mu) * rstd * g2.y + b2.y,
                       (c.z - mu) * rstd * g2.z + b2.z, (c.w - mu) * rstd * g2.w + b2.w};
    *(float4*)(y + lane * 4) = o1;
    *(float4*)(y + 256 + lane * 4) = o2;
    if (outb) {
        unsigned short* yb = outb + (size_t)row * 512;
        const us4 p1 = {f2bf(o1.x), f2bf(o1.y), f2bf(o1.z), f2bf(o1.w)};
        const us4 p2 = {f2bf(o2.x), f2bf(o2.y), f2bf(o2.z), f2bf(o2.w)};
        *(us4*)(yb + lane * 4) = p1;
        *(us4*)(yb + 256 + lane * 4) = p2;
    }
}

// ---------------- persistent GRU: 8 WGs x 4 waves, one launch, 512 steps ----------------------
// wave w (global 0..31) owns h-cols [w*16, w*16+16); weights resident in VGPRs (bf16 frags).
// h state fp32 in registers; h exchanged via ping-pong global bf16 buffers.
// Barrier: __syncthreads -> tid0 RELEASE fetch_add -> wave0 ACQUIRE poll (s_sleep backoff)
// -> __syncthreads -> per-wave ACQUIRE load. gout deferred past arrive; xp[t+1] prefetched.
__global__ __launch_bounds__(256, 1)
void gru_persist(const float* __restrict__ rk,      // gru_rk [512][1536] fp32
                 const float* __restrict__ xp,      // [8192][1536] fp32 (bias0 included)
                 const float* __restrict__ rb,      // recurrent bias [1536]
                 unsigned short* __restrict__ hbuf, // [2][16*512] bf16 (buf0 zeroed)
                 unsigned short* __restrict__ goutb,// [8192][512] bf16
                 unsigned int* __restrict__ bar)    // zeroed
{
    const int tid = threadIdx.x;
    const int wv = tid >> 6, l = tid & 63;
    const int wg = blockIdx.x * 4 + wv;  // 0..31
    const int lo16 = l & 15;
    const int hi4 = l >> 4;              // 0..3
    const int gc = wg * 16 + lo16;       // this lane's output h-col

    // ---- preload B fragments: B[g][kt], lane slot j <-> k = kt*32 + hi4*8 + j
    bf16x8 B[3][16];
#pragma unroll
    for (int g = 0; g < 3; ++g)
#pragma unroll
        for (int kt = 0; kt < 16; ++kt) {
            bf16x8 bv;
#pragma unroll
            for (int j = 0; j < 8; ++j) {
                const int k = kt * 32 + hi4 * 8 + j;
                bv[j] = (short)f2bf(rk[(size_t)k * 1536 + g * 512 + gc]);
            }
            B[g][kt] = bv;
        }
    const float rbz = rb[gc], rbr = rb[512 + gc], rbh = rb[1024 + gc];
    float hst[4] = {0.f, 0.f, 0.f, 0.f};

    // prefetch xp for t=0
    float xzv[4], xrv[4], xhv[4];
#pragma unroll
    for (int j = 0; j < 4; ++j) {
        const float* xrow = xp + ((size_t)((hi4 * 4 + j) * 512)) * 1536 + gc;
        xzv[j] = xrow[0]; xrv[j] = xrow[512]; xhv[j] = xrow[1024];
    }

    for (int t = 0; t < 512; ++t) {
        const unsigned short* hr = hbuf + (size_t)(t & 1) * (16 * 512);
        unsigned short* hw = hbuf + (size_t)((t + 1) & 1) * (16 * 512);
        // A frags: lane reads h[b=lo16][k..k+7] contiguous (same k-map as B)
        bf16x8 A[16];
#pragma unroll
        for (int kt = 0; kt < 16; ++kt)
            A[kt] = *(const bf16x8*)(hr + lo16 * 512 + kt * 32 + hi4 * 8);
        f32x4 accz = {0.f, 0.f, 0.f, 0.f};
        f32x4 accr = {0.f, 0.f, 0.f, 0.f};
        f32x4 acch = {0.f, 0.f, 0.f, 0.f};
#pragma unroll
        for (int kt = 0; kt < 16; ++kt) {
            accz = __builtin_amdgcn_mfma_f32_16x16x32_bf16(A[kt], B[0][kt], accz, 0, 0, 0);
            accr = __builtin_amdgcn_mfma_f32_16x16x32_bf16(A[kt], B[1][kt], accr, 0, 0, 0);
            acch = __builtin_amdgcn_mfma_f32_16x16x32_bf16(A[kt], B[2][kt], acch, 0, 0, 0);
        }
        // gates + state update; D layout: row b = hi4*4 + j, col = lo16
        float hn[4];
#pragma unroll
        for (int j = 0; j < 4; ++j) {
            const int b = hi4 * 4 + j;
            const float z = sigmoidf_(xzv[j] + accz[j] + rbz);
            const float r = sigmoidf_(xrv[j] + accr[j] + rbr);
            const float hh = fmaxf(xhv[j] + r * (acch[j] + rbh), 0.f);
            const float hnew = z * hst[j] + (1.f - z) * hh;
            hst[j] = hnew; hn[j] = hnew;
            hw[b * 512 + gc] = f2bf(hnew);
        }
        __syncthreads();   // all WG h-stores drained to L2
        if (tid == 0)
            __hip_atomic_fetch_add(bar, 1u, __ATOMIC_RELEASE, __HIP_MEMORY_SCOPE_AGENT);
        // deferred (off critical path): gout stores for step t
#pragma unroll
        for (int j = 0; j < 4; ++j)
            goutb[((size_t)((hi4 * 4 + j) * 512 + t)) * 512 + gc] = f2bf(hn[j]);
        if (t < 511) {
            // prefetch xp for t+1 (completes during spin)
#pragma unroll
            for (int j = 0; j < 4; ++j) {
                const float* xrow = xp + ((size_t)((hi4 * 4 + j) * 512 + t + 1)) * 1536 + gc;
                xzv[j] = xrow[0]; xrv[j] = xrow[512]; xhv[j] = xrow[1024];
            }
            if (tid < 64) {
                const unsigned int target = 8u * (unsigned int)(t + 1);
                while (__hip_atomic_load(bar, __ATOMIC_ACQUIRE, __HIP_MEMORY_SCOPE_AGENT) < target)
                    __builtin_amdgcn_s_sleep(2);
            }
            __syncthreads();
            unsigned int vv = __hip_atomic_load(bar, __ATOMIC_ACQUIRE, __HIP_MEMORY_SCOPE_AGENT);
            asm volatile("" :: "v"(vv));   // keep per-wave acquire alive
        }
    }
}

extern "C" void kernel_launch(void* const* d_in, const int* in_sizes, int n_in,
                              void* d_out, int out_size, void* d_ws, size_t ws_size,
                              hipStream_t stream)
{
    const float* x     = (const float*)d_in[0];
    const float* Wq    = (const float*)d_in[1];
    const float* bq    = (const float*)d_in[2];
    const float* Wk    = (const float*)d_in[3];
    const float* bk    = (const float*)d_in[4];
    const float* Wv    = (const float*)d_in[5];
    const float* bv    = (const float*)d_in[6];
    const float* Wo    = (const float*)d_in[7];
    const float* bo    = (const float*)d_in[8];
    const float* ln1g  = (const float*)d_in[9];
    const float* ln1b  = (const float*)d_in[10];
    const float* gruk  = (const float*)d_in[11];
    const float* grurk = (const float*)d_in[12];
    const float* grub  = (const float*)d_in[13];
    const float* Wd    = (const float*)d_in[14];
    const float* bd    = (const float*)d_in[15];
    const float* ln2g  = (const float*)d_in[16];
    const float* ln2b  = (const float*)d_in[17];
    float* out = (float*)d_out;

    char* base = (char*)d_ws;
    const size_t MB = 1024 * 1024;
    float*          Q0   = (float*)base;                   // 48 MB: q/k/v -> xp -> dense-out
    float*          R4   = (float*)(base + 48 * MB);       // 16 MB: x1
    unsigned short* S1   = (unsigned short*)(base + 64 * MB); // 8 MB: xb -> ctxb -> x1b -> goutb
    unsigned short* WT   = (unsigned short*)(base + 72 * MB); // 4 MB weights
    unsigned short* wqT  = WT;                  // 512x512
    unsigned short* wkT  = WT + 256 * 1024;
    unsigned short* wvT  = WT + 512 * 1024;
    unsigned short* woT  = WT + 768 * 1024;
    unsigned short* gkT  = WT + 1024 * 1024;    // 1536x512
    unsigned short* wdT  = WT + 1792 * 1024;    // 512x512
    unsigned short* hbuf = (unsigned short*)(base + 76 * MB); // 2*16*512 bf16
    unsigned int*   bar  = (unsigned int*)(base + 76 * MB + 64 * 1024);

    float* q = Q0;
    float* k = Q0 + (size_t)4 * MB;   // 4M floats = 16MB
    float* v = Q0 + (size_t)8 * MB;
    float* xpbuf = Q0;                // 8192x1536 f32 (after q/k/v dead)
    float* dout  = Q0;                // 8192x512  f32 (after xp dead)

    const dim3 blk(256);
    const dim3 g512(8192 / 128, 512 / 128);    // 64 x 4
    const dim3 g1536(8192 / 128, 1536 / 128);  // 64 x 12

    // input x -> bf16
    f2bf_kernel<<<dim3(4096), blk, 0, stream>>>(x, S1);
    // weight transposes ([K][N] f32 -> [N][K] bf16)
    transpose_bf16<<<dim3(16, 16), blk, 0, stream>>>(Wq, wqT, 512, 512);
    transpose_bf16<<<dim3(16, 16), blk, 0, stream>>>(Wk, wkT, 512, 512);
    transpose_bf16<<<dim3(16, 16), blk, 0, stream>>>(Wv, wvT, 512, 512);
    transpose_bf16<<<dim3(16, 16), blk, 0, stream>>>(Wo, woT, 512, 512);
    transpose_bf16<<<dim3(48, 16), blk, 0, stream>>>(gruk, gkT, 512, 1536);
    transpose_bf16<<<dim3(16, 16), blk, 0, stream>>>(Wd, wdT, 512, 512);
    // QKV projections (bf16 MFMA)
    gemm_bf16<<<g512, blk, 0, stream>>>(S1, wqT, bq, nullptr, q, 8192, 512, 512);
    gemm_bf16<<<g512, blk, 0, stream>>>(S1, wkT, bk, nullptr, k, 8192, 512, 512);
    gemm_bf16<<<g512, blk, 0, stream>>>(S1, wvT, bv, nullptr, v, 8192, 512, 512);
    // attention (fp32 compute, bf16 ctx out into S1)
    attn_f32<<<dim3(1024), blk, 0, stream>>>(q, k, v, S1);
    // output projection + residual -> R4, then LN1 (f32 in place + bf16 side out into S1)
    gemm_bf16<<<g512, blk, 0, stream>>>(S1, woT, bo, x, R4, 8192, 512, 512);
    ln_f32<<<dim3(2048), blk, 0, stream>>>(R4, R4, ln1g, ln1b, S1);
    // GRU input projection xp = x1 @ gru_k + gru_b[0]
    gemm_bf16<<<g1536, blk, 0, stream>>>(S1, gkT, grub, nullptr, xpbuf, 8192, 1536, 512);
    // persistent GRU
    hipMemsetAsync(hbuf, 0, 2 * 16 * 512 * sizeof(unsigned short), stream);
    hipMemsetAsync(bar, 0, sizeof(unsigned int), stream);
    gru_persist<<<dim3(NWG), blk, 0, stream>>>(grurk, xpbuf, grub + 1536, hbuf, S1, bar);
    // Dense + residual x1 -> dout, then LN2 -> out
    gemm_bf16<<<g512, blk, 0, stream>>>(S1, wdT, bd, R4, dout, 8192, 512, 512);
    ln_f32<<<dim3(2048), blk, 0, stream>>>(dout, out, ln2g, ln2b, nullptr);
}